// Round 2
// baseline (967.651 us; speedup 1.0000x reference)
//
#include <hip/hip_runtime.h>
#include <hip/hip_bf16.h>
#include <cstdint>

// Problem: B=256, N0=64, D0=128, N1=64, D1=128 (all fp32 in/out).
// u[b,n1,n0,d1] = sum_d0 x[b,n0,d0]*W[n1,n0,d0,d1]
// s = sum_n0 u ; logit = (u . s)/sqrt(128) ; c = softmax_n1(logit) + bias
// out[b,n1,d1] = sum_n0 u*c
//
// ws layout: u bf16 [B][N1][N0][D1]      @ 0          (268435456 B)
//            logits f32 [B][N1][N0]      @ 268435456  (4194304 B)
//            cc/xbf shared region        @ 272629760  (4194304 B)
//              - Px writes xbf (bf16 [B][N0][D0], 4 MB), K1 reads it
//              - K3 later overwrites with cc (f32 [B][N1][N0]) after K1 done

#define BB 256
#define NN0 64
#define DD0 128
#define NN1 64
#define DD1 128

typedef __attribute__((ext_vector_type(8))) short bf16x8;
typedef __attribute__((ext_vector_type(4))) float f32x4;

__device__ __forceinline__ ushort f2bf(float f) {
  uint32_t b = __float_as_uint(f);
  b += 0x7FFFu + ((b >> 16) & 1u);      // RNE
  return (ushort)(b >> 16);
}
__device__ __forceinline__ float bf2f(ushort h) {
  return __uint_as_float(((uint32_t)h) << 16);
}

__device__ __forceinline__ void gld_lds16(const void* g, void* l) {
  __builtin_amdgcn_global_load_lds(
      (const __attribute__((address_space(1))) void*)g,
      (__attribute__((address_space(3))) void*)l, 16, 0, 0);
}

// ---------------- Px: x fp32 -> bf16
__global__ __launch_bounds__(512) void px_cvt(
    const float* __restrict__ x, ushort* __restrict__ xbf)
{
  int i = blockIdx.x * 512 + threadIdx.x;   // 524288 float4 chunks total
  float4 v = *reinterpret_cast<const float4*>(x + (size_t)i * 4);
  ushort4 h;
  h.x = f2bf(v.x); h.y = f2bf(v.y); h.z = f2bf(v.z); h.w = f2bf(v.w);
  *reinterpret_cast<ushort4*>(xbf + (size_t)i * 4) = h;
}

// ---------------- K1: u = x @ W  (per (n1,n0): [256x128] = [256x128]x[128x128])
__global__ __launch_bounds__(512, 6) void k1_gemm(
    const ushort* __restrict__ xbf, const float* __restrict__ W,
    ushort* __restrict__ u)
{
  __shared__ char lds[49152];           // A: 32768 B (256 rows x 64k bf16), Bt: 16384 B (128 n x 64k)
  char* Alds = lds;
  char* Blds = lds + 32768;

  const int bid = blockIdx.x;
  const int n1 = bid >> 6, n0 = bid & 63;
  const int t = threadIdx.x;
  const int lane = t & 63, wave = t >> 6;
  const int wm = wave >> 1, wn = wave & 1;   // 4 M-waves x 2 N-waves

  const ushort* xb = xbf + n0 * DD0;                               // + b*8192 + d0
  const float* Wb = W + ((size_t)n1 * NN0 + n0) * (DD0 * DD1);     // [d0][d1]
  ushort* ub = u + ((size_t)n1 * 8192 + (size_t)n0 * 128);         // + b*524288 + d1

  f32x4 acc[4][4];
#pragma unroll
  for (int i = 0; i < 4; ++i)
#pragma unroll
    for (int j = 0; j < 4; ++j) acc[i][j] = {0.f, 0.f, 0.f, 0.f};

  // per-lane constants for A staging (source-pre-swizzle for linear gld_lds dest)
  const int arow_in_seg = lane >> 3;                    // 0..7
  const int acsrc = (lane & 7) ^ arow_in_seg;           // chunk to fetch

  // B half-0 register prefetch
  float4 breg[4];
#pragma unroll
  for (int i = 0; i < 4; ++i) {
    int c = t + i * 512;                // k = c&63 = lane, nch = wave + i*8
    int k = c & 63, nch = c >> 6;
    breg[i] = *reinterpret_cast<const float4*>(Wb + (size_t)k * 128 + nch * 4);
  }

  for (int khalf = 0; khalf < 2; ++khalf) {
    const int k0 = khalf * 64;
    if (khalf) __syncthreads();         // prev MFMA must finish before LDS overwrite

    // --- stage A via global_load_lds (linear dest, pre-swizzled source)
#pragma unroll
    for (int s = 0; s < 4; ++s) {
      int seg = wave * 4 + s;           // 0..31, rows seg*8..seg*8+7
      int row = seg * 8 + arow_in_seg;
      const ushort* src = xb + (size_t)row * 8192 + k0 + acsrc * 8;
      gld_lds16(src, Alds + seg * 1024);
    }
    // --- stage B: cvt + transposed swizzled scatter (contiguous per instr)
#pragma unroll
    for (int i = 0; i < 4; ++i) {
      int c = t + i * 512;
      int k = c & 63, nch = c >> 6;
      ushort h0 = f2bf(breg[i].x), h1 = f2bf(breg[i].y),
             h2 = f2bf(breg[i].z), h3 = f2bf(breg[i].w);
      int n = nch * 4;
      *(ushort*)(Blds + (((n + 0) * 128 + k * 2) ^ (((n + 0) & 7) << 4))) = h0;
      *(ushort*)(Blds + (((n + 1) * 128 + k * 2) ^ (((n + 1) & 7) << 4))) = h1;
      *(ushort*)(Blds + (((n + 2) * 128 + k * 2) ^ (((n + 2) & 7) << 4))) = h2;
      *(ushort*)(Blds + (((n + 3) * 128 + k * 2) ^ (((n + 3) & 7) << 4))) = h3;
    }
    __syncthreads();

    // prefetch B regs for half 1 (overlaps MFMA below)
    if (khalf == 0) {
#pragma unroll
      for (int i = 0; i < 4; ++i) {
        int c = t + i * 512;
        int k = c & 63, nch = c >> 6;
        breg[i] = *reinterpret_cast<const float4*>(Wb + (size_t)(64 + k) * 128 + nch * 4);
      }
    }

    // --- MFMA over this K-half
#pragma unroll
    for (int kk = 0; kk < 64; kk += 32) {
      const int kb = kk + (lane >> 4) * 8;
      bf16x8 af[4], bfr[4];
#pragma unroll
      for (int mf = 0; mf < 4; ++mf) {
        int row = wm * 64 + mf * 16 + (lane & 15);
        int byte = (row * 128 + kb * 2) ^ ((row & 7) << 4);
        af[mf] = *reinterpret_cast<bf16x8*>(Alds + byte);
      }
#pragma unroll
      for (int nf = 0; nf < 4; ++nf) {
        int n = wn * 64 + nf * 16 + (lane & 15);
        int byte = (n * 128 + kb * 2) ^ ((n & 7) << 4);
        bfr[nf] = *reinterpret_cast<bf16x8*>(Blds + byte);
      }
#pragma unroll
      for (int mf = 0; mf < 4; ++mf)
#pragma unroll
        for (int nf = 0; nf < 4; ++nf)
          acc[mf][nf] = __builtin_amdgcn_mfma_f32_16x16x32_bf16(af[mf], bfr[nf], acc[mf][nf], 0, 0, 0);
    }
  }

  // epilogue: stage C through LDS (rows of 128 d1 bf16 = 256 B) for vector global writes.
#pragma unroll
  for (int half = 0; half < 2; ++half) {
    __syncthreads();
    if ((wm >> 1) == half) {            // waves holding rows [half*128, half*128+128)
      int wml = wm & 1;
#pragma unroll
      for (int mf = 0; mf < 4; ++mf) {
        int rowb = wml * 64 + mf * 16 + (lane >> 4) * 4;
#pragma unroll
        for (int nf = 0; nf < 4; ++nf) {
          int col = wn * 64 + nf * 16 + (lane & 15);
#pragma unroll
          for (int r = 0; r < 4; ++r) {
            int rr = rowb + r;
            int byte = (rr * 256 + col * 2) ^ ((rr & 7) << 4);
            *reinterpret_cast<ushort*>(lds + byte) = f2bf(acc[mf][nf][r]);
          }
        }
      }
    }
    __syncthreads();
#pragma unroll
    for (int i = 0; i < 4; ++i) {
      int c = t + i * 512;              // 2048 x 16B chunks = 32 KB
      int rowl = c >> 4;
      int cb = (c & 15) * 16;
      int sbyte = (rowl * 256 + cb) ^ ((rowl & 7) << 4);
      uint4 v = *reinterpret_cast<uint4*>(lds + sbyte);
      int row = half * 128 + rowl;      // global b
      *reinterpret_cast<uint4*>(ub + (size_t)row * 524288 + cb / 2) = v;
    }
  }
}

// ---------------- K2: s = sum_n0 u ; logits = (u . s)/sqrt(128)
__global__ __launch_bounds__(256) void k2_logits(
    const ushort* __restrict__ u, float* __restrict__ logits)
{
  const int bid = blockIdx.x;           // b*64 + n1
  const ushort* up = u + (size_t)bid * 8192;   // [n0][d1] 64x128
  const int t = threadIdx.x;

  __shared__ float part[8][128];
  __shared__ float sS[128];
  __shared__ float part2[256];

  {
    int d4 = (t & 31) * 4;
    int g = t >> 5;                     // n0 group of 8
    float4 a = {0, 0, 0, 0};
    for (int n0 = g * 8; n0 < g * 8 + 8; ++n0) {
      ushort4 v = *reinterpret_cast<const ushort4*>(up + n0 * 128 + d4);
      a.x += bf2f(v.x); a.y += bf2f(v.y); a.z += bf2f(v.z); a.w += bf2f(v.w);
    }
    *reinterpret_cast<float4*>(&part[g][d4]) = a;
  }
  __syncthreads();
  if (t < 128) {
    float s = 0;
#pragma unroll
    for (int g = 0; g < 8; ++g) s += part[g][t];
    sS[t] = s;
  }
  __syncthreads();
  {
    int n0 = t >> 2, q = t & 3;
    float acc = 0;
#pragma unroll
    for (int j = 0; j < 32; j += 4) {
      int d = q * 32 + j;
      ushort4 v = *reinterpret_cast<const ushort4*>(up + n0 * 128 + d);
      acc += bf2f(v.x) * sS[d] + bf2f(v.y) * sS[d + 1] + bf2f(v.z) * sS[d + 2] + bf2f(v.w) * sS[d + 3];
    }
    part2[t] = acc;
  }
  __syncthreads();
  if (t < 64) {
    float l = (part2[t * 4] + part2[t * 4 + 1] + part2[t * 4 + 2] + part2[t * 4 + 3]) * 0.08838834764831845f;
    logits[(size_t)bid * 64 + t] = l;
  }
}

// ---------------- K3: softmax over n1 (per (b,n0)) + bias
__global__ __launch_bounds__(64) void k3_softmax(
    const float* __restrict__ logits, const float* __restrict__ bias,
    float* __restrict__ cc)
{
  const int b = blockIdx.x;
  const int t = threadIdx.x;            // = n0
  __shared__ float L[64][64];           // [n1][n0]
  const float* lp = logits + (size_t)b * 4096;
  for (int i = 0; i < 64; ++i) L[i][t] = lp[i * 64 + t];
  __syncthreads();
  float m = -1e30f;
#pragma unroll
  for (int n1 = 0; n1 < 64; ++n1) m = fmaxf(m, L[n1][t]);
  float sum = 0.f;
#pragma unroll
  for (int n1 = 0; n1 < 64; ++n1) {
    float e = __expf(L[n1][t] - m);
    L[n1][t] = e;
    sum += e;
  }
  float inv = 1.0f / sum;
  float* cp = cc + (size_t)b * 4096;
  for (int n1 = 0; n1 < 64; ++n1)
    cp[n1 * 64 + t] = L[n1][t] * inv + bias[n1 * 64 + t];
}

// ---------------- K4: out[b,n1,d1] = sum_n0 u * c
__global__ __launch_bounds__(128) void k4_out(
    const ushort* __restrict__ u, const float* __restrict__ cc,
    float* __restrict__ out)
{
  const int bid = blockIdx.x;           // b*64 + n1
  const ushort* up = u + (size_t)bid * 8192;
  const int t = threadIdx.x;
  __shared__ float cL[64];
  __shared__ float part[4][128];
  if (t < 64) cL[t] = cc[(size_t)bid * 64 + t];
  __syncthreads();
  int d4 = (t & 31) * 4, g = t >> 5;    // g: n0 group of 16
  float4 a = {0, 0, 0, 0};
  for (int n0 = g * 16; n0 < g * 16 + 16; ++n0) {
    ushort4 v = *reinterpret_cast<const ushort4*>(up + n0 * 128 + d4);
    float c = cL[n0];
    a.x += bf2f(v.x) * c; a.y += bf2f(v.y) * c; a.z += bf2f(v.z) * c; a.w += bf2f(v.w) * c;
  }
  *reinterpret_cast<float4*>(&part[g][d4]) = a;
  __syncthreads();
  if (t < 128) {
    float r = part[0][t] + part[1][t] + part[2][t] + part[3][t];
    out[(size_t)bid * 128 + t] = r;
  }
}

extern "C" void kernel_launch(void* const* d_in, const int* in_sizes, int n_in,
                              void* d_out, int out_size, void* d_ws, size_t ws_size,
                              hipStream_t stream) {
  const float* x = (const float*)d_in[0];
  const float* W = (const float*)d_in[1];
  const float* bias = (const float*)d_in[2];
  float* out = (float*)d_out;

  ushort* u = (ushort*)d_ws;                                   // 268435456 B
  float* logits = (float*)((char*)d_ws + 268435456u);          // 4194304 B
  char* ccxbf = (char*)d_ws + 272629760u;                      // 4194304 B shared
  ushort* xbf = (ushort*)ccxbf;     // live Px..K1
  float* cc = (float*)ccxbf;        // live K3..K4 (overwrites xbf after K1 done)

  hipLaunchKernelGGL(px_cvt,     dim3(1024),      dim3(512), 0, stream, x, xbf);
  hipLaunchKernelGGL(k1_gemm,    dim3(NN1 * NN0), dim3(512), 0, stream, xbf, W, u);
  hipLaunchKernelGGL(k2_logits,  dim3(BB * NN1),  dim3(256), 0, stream, u, logits);
  hipLaunchKernelGGL(k3_softmax, dim3(BB),        dim3(64),  0, stream, logits, bias, cc);
  hipLaunchKernelGGL(k4_out,     dim3(BB * NN1),  dim3(128), 0, stream, u, cc, out);
}

// Round 3
// 230.250 us; speedup vs baseline: 4.2026x; 4.2026x over previous
//
#include <hip/hip_runtime.h>
#include <hip/hip_bf16.h>
#include <cstdint>

// Problem: B=256, N0=64, D0=128, N1=64, D1=128 (all fp32 in/out).
// u[b,n1,n0,d1] = sum_d0 x[b,n0,d0]*W[n1,n0,d0,d1]
// s = sum_n0 u ; logit = (u . s)/sqrt(128) ; c = softmax_n1(logit) + bias
// out[b,n1,d1] = sum_n0 u*c
//
// ws layout: u bf16 [B][N1][N0][D1]      @ 0          (268435456 B)
//            logits f32 [B][N1][N0]      @ 268435456  (4194304 B)
//            cc/xbf shared region        @ 272629760  (4194304 B)

#define BB 256
#define NN0 64
#define DD0 128
#define NN1 64
#define DD1 128

typedef __attribute__((ext_vector_type(8))) short bf16x8;
typedef __attribute__((ext_vector_type(4))) float f32x4;

__device__ __forceinline__ ushort f2bf(float f) {
  uint32_t b = __float_as_uint(f);
  b += 0x7FFFu + ((b >> 16) & 1u);      // RNE
  return (ushort)(b >> 16);
}
__device__ __forceinline__ float bf2f(ushort h) {
  return __uint_as_float(((uint32_t)h) << 16);
}

__device__ __forceinline__ void gld_lds16(const void* g, void* l) {
  __builtin_amdgcn_global_load_lds(
      (const __attribute__((address_space(1))) void*)g,
      (__attribute__((address_space(3))) void*)l, 16, 0, 0);
}

// ---------------- Px: x fp32 -> bf16
__global__ __launch_bounds__(512) void px_cvt(
    const float* __restrict__ x, ushort* __restrict__ xbf)
{
  int i = blockIdx.x * 512 + threadIdx.x;   // 524288 float4 chunks total
  float4 v = *reinterpret_cast<const float4*>(x + (size_t)i * 4);
  ushort4 h;
  h.x = f2bf(v.x); h.y = f2bf(v.y); h.z = f2bf(v.z); h.w = f2bf(v.w);
  *reinterpret_cast<ushort4*>(xbf + (size_t)i * 4) = h;
}

// ---------------- K1: u = x @ W  (per (n1,n0): [256x128] = [256x128]x[128x128])
// launch_bounds (512,4): VGPR cap 128 (2 blocks/CU, 16 waves). acc needs 64;
// ~105 total fits. NEVER set min-waves higher: (512,6) spilled acc -> 880us.
__global__ __launch_bounds__(512, 4) void k1_gemm(
    const ushort* __restrict__ xbf, const float* __restrict__ W,
    ushort* __restrict__ u)
{
  __shared__ char lds[49152];           // A: 32768 B (256 rows x 64k bf16), Bt: 16384 B (128 n x 64k)
  char* Alds = lds;
  char* Blds = lds + 32768;

  // XCD-contiguous remap: per XCD, sequential blocks share n0 (same x slice -> L2 hits)
  const int bid0 = blockIdx.x;
  const int bid = (bid0 & 7) * 512 + (bid0 >> 3);   // bijective (4096 = 8*512)
  const int n0 = bid >> 6, n1 = bid & 63;           // 64 consecutive bids: same n0
  const int t = threadIdx.x;
  const int lane = t & 63, wave = t >> 6;
  const int wm = wave >> 1, wn = wave & 1;          // 4 M-waves x 2 N-waves

  const ushort* xb = xbf + n0 * DD0;                               // + b*8192 + d0
  const float* Wb = W + ((size_t)n1 * NN0 + n0) * (DD0 * DD1);     // [d0][d1]
  ushort* ub = u + ((size_t)n1 * 8192 + (size_t)n0 * 128);         // + b*524288 + d1

  f32x4 acc[4][4];
#pragma unroll
  for (int i = 0; i < 4; ++i)
#pragma unroll
    for (int j = 0; j < 4; ++j) acc[i][j] = {0.f, 0.f, 0.f, 0.f};

  // per-lane constants for A staging (source-pre-swizzle for linear gld_lds dest)
  const int arow_in_seg = lane >> 3;                // 0..7
  const int acsrc = (lane & 7) ^ arow_in_seg;       // chunk to fetch

  // B scalar-gather addressing (R1-proven: coalesced 4B over n, 0 conflicts)
  const int c0 = t, c1 = t + 512;
  const int bn0 = c0 & 127, bkc0 = c0 >> 7;         // n row, k-chunk (8 k's)
  const int bn1 = c1 & 127, bkc1 = c1 >> 7;

  float hh[16];
  // prologue: issue half-0 W loads
#pragma unroll
  for (int j = 0; j < 8; ++j) hh[j]     = Wb[(size_t)(bkc0 * 8 + j) * 128 + bn0];
#pragma unroll
  for (int j = 0; j < 8; ++j) hh[8 + j] = Wb[(size_t)(bkc1 * 8 + j) * 128 + bn1];

#pragma unroll
  for (int khalf = 0; khalf < 2; ++khalf) {
    const int k0 = khalf * 64;
    if (khalf) __syncthreads();         // prev MFMA must finish before LDS overwrite

    // --- stage A via global_load_lds (linear dest, pre-swizzled source)
#pragma unroll
    for (int s = 0; s < 4; ++s) {
      int seg = wave * 4 + s;           // 0..31, rows seg*8..seg*8+7
      int row = seg * 8 + arow_in_seg;
      const ushort* src = xb + (size_t)row * 8192 + k0 + acsrc * 8;
      gld_lds16(src, Alds + seg * 1024);
    }
    // --- stage B: pack prefetched W scalars, swizzled uint4 writes
    {
      uint32_t p[8];
#pragma unroll
      for (int q = 0; q < 8; ++q)
        p[q] = (uint32_t)f2bf(hh[q * 2]) | ((uint32_t)f2bf(hh[q * 2 + 1]) << 16);
      *reinterpret_cast<uint4*>(Blds + ((bn0 * 128 + bkc0 * 16) ^ ((bn0 & 7) << 4))) =
          make_uint4(p[0], p[1], p[2], p[3]);
      *reinterpret_cast<uint4*>(Blds + ((bn1 * 128 + bkc1 * 16) ^ ((bn1 & 7) << 4))) =
          make_uint4(p[4], p[5], p[6], p[7]);
    }
    // prefetch half-1 W scalars (overlaps barrier + MFMA below)
    if (khalf == 0) {
#pragma unroll
      for (int j = 0; j < 8; ++j) hh[j]     = Wb[(size_t)(64 + bkc0 * 8 + j) * 128 + bn0];
#pragma unroll
      for (int j = 0; j < 8; ++j) hh[8 + j] = Wb[(size_t)(64 + bkc1 * 8 + j) * 128 + bn1];
    }
    __syncthreads();

    // --- MFMA over this K-half
#pragma unroll
    for (int kk = 0; kk < 64; kk += 32) {
      const int kb = kk + (lane >> 4) * 8;
      bf16x8 af[4], bfr[4];
#pragma unroll
      for (int mf = 0; mf < 4; ++mf) {
        int row = wm * 64 + mf * 16 + (lane & 15);
        int byte = (row * 128 + kb * 2) ^ ((row & 7) << 4);
        af[mf] = *reinterpret_cast<bf16x8*>(Alds + byte);
      }
#pragma unroll
      for (int nf = 0; nf < 4; ++nf) {
        int n = wn * 64 + nf * 16 + (lane & 15);
        int byte = (n * 128 + kb * 2) ^ ((n & 7) << 4);
        bfr[nf] = *reinterpret_cast<bf16x8*>(Blds + byte);
      }
#pragma unroll
      for (int mf = 0; mf < 4; ++mf)
#pragma unroll
        for (int nf = 0; nf < 4; ++nf)
          acc[mf][nf] = __builtin_amdgcn_mfma_f32_16x16x32_bf16(af[mf], bfr[nf], acc[mf][nf], 0, 0, 0);
    }
  }

  // epilogue: stage C through LDS (rows of 128 d1 bf16 = 256 B) for vector global writes.
#pragma unroll
  for (int half = 0; half < 2; ++half) {
    __syncthreads();
    if ((wm >> 1) == half) {            // waves holding rows [half*128, half*128+128)
      int wml = wm & 1;
#pragma unroll
      for (int mf = 0; mf < 4; ++mf) {
        int rowb = wml * 64 + mf * 16 + (lane >> 4) * 4;
#pragma unroll
        for (int nf = 0; nf < 4; ++nf) {
          int col = wn * 64 + nf * 16 + (lane & 15);
#pragma unroll
          for (int r = 0; r < 4; ++r) {
            int rr = rowb + r;
            int byte = (rr * 256 + col * 2) ^ ((rr & 7) << 4);
            *reinterpret_cast<ushort*>(lds + byte) = f2bf(acc[mf][nf][r]);
          }
        }
      }
    }
    __syncthreads();
#pragma unroll
    for (int i = 0; i < 4; ++i) {
      int c = t + i * 512;              // 2048 x 16B chunks = 32 KB
      int rowl = c >> 4;
      int cb = (c & 15) * 16;
      int sbyte = (rowl * 256 + cb) ^ ((rowl & 7) << 4);
      uint4 v = *reinterpret_cast<uint4*>(lds + sbyte);
      int row = half * 128 + rowl;      // global b
      *reinterpret_cast<uint4*>(ub + (size_t)row * 524288 + cb / 2) = v;
    }
  }
}

// ---------------- K2: s = sum_n0 u ; logits = (u . s)/sqrt(128)
__global__ __launch_bounds__(256) void k2_logits(
    const ushort* __restrict__ u, float* __restrict__ logits)
{
  const int bid = blockIdx.x;           // b*64 + n1
  const ushort* up = u + (size_t)bid * 8192;   // [n0][d1] 64x128
  const int t = threadIdx.x;

  __shared__ float part[8][128];
  __shared__ float sS[128];
  __shared__ float part2[256];

  {
    int d4 = (t & 31) * 4;
    int g = t >> 5;                     // n0 group of 8
    float4 a = {0, 0, 0, 0};
    for (int n0 = g * 8; n0 < g * 8 + 8; ++n0) {
      ushort4 v = *reinterpret_cast<const ushort4*>(up + n0 * 128 + d4);
      a.x += bf2f(v.x); a.y += bf2f(v.y); a.z += bf2f(v.z); a.w += bf2f(v.w);
    }
    *reinterpret_cast<float4*>(&part[g][d4]) = a;
  }
  __syncthreads();
  if (t < 128) {
    float s = 0;
#pragma unroll
    for (int g = 0; g < 8; ++g) s += part[g][t];
    sS[t] = s;
  }
  __syncthreads();
  {
    int n0 = t >> 2, q = t & 3;
    float acc = 0;
#pragma unroll
    for (int j = 0; j < 32; j += 4) {
      int d = q * 32 + j;
      ushort4 v = *reinterpret_cast<const ushort4*>(up + n0 * 128 + d);
      acc += bf2f(v.x) * sS[d] + bf2f(v.y) * sS[d + 1] + bf2f(v.z) * sS[d + 2] + bf2f(v.w) * sS[d + 3];
    }
    part2[t] = acc;
  }
  __syncthreads();
  if (t < 64) {
    float l = (part2[t * 4] + part2[t * 4 + 1] + part2[t * 4 + 2] + part2[t * 4 + 3]) * 0.08838834764831845f;
    logits[(size_t)bid * 64 + t] = l;
  }
}

// ---------------- K3: softmax over n1 (per (b,n0)) + bias
__global__ __launch_bounds__(64) void k3_softmax(
    const float* __restrict__ logits, const float* __restrict__ bias,
    float* __restrict__ cc)
{
  const int b = blockIdx.x;
  const int t = threadIdx.x;            // = n0
  __shared__ float L[64][64];           // [n1][n0]
  const float* lp = logits + (size_t)b * 4096;
  for (int i = 0; i < 64; ++i) L[i][t] = lp[i * 64 + t];
  __syncthreads();
  float m = -1e30f;
#pragma unroll
  for (int n1 = 0; n1 < 64; ++n1) m = fmaxf(m, L[n1][t]);
  float sum = 0.f;
#pragma unroll
  for (int n1 = 0; n1 < 64; ++n1) {
    float e = __expf(L[n1][t] - m);
    L[n1][t] = e;
    sum += e;
  }
  float inv = 1.0f / sum;
  float* cp = cc + (size_t)b * 4096;
  for (int n1 = 0; n1 < 64; ++n1)
    cp[n1 * 64 + t] = L[n1][t] * inv + bias[n1 * 64 + t];
}

// ---------------- K4: out[b,n1,d1] = sum_n0 u * c
__global__ __launch_bounds__(128) void k4_out(
    const ushort* __restrict__ u, const float* __restrict__ cc,
    float* __restrict__ out)
{
  const int bid = blockIdx.x;           // b*64 + n1
  const ushort* up = u + (size_t)bid * 8192;
  const int t = threadIdx.x;
  __shared__ float cL[64];
  __shared__ float part[4][128];
  if (t < 64) cL[t] = cc[(size_t)bid * 64 + t];
  __syncthreads();
  int d4 = (t & 31) * 4, g = t >> 5;    // g: n0 group of 16
  float4 a = {0, 0, 0, 0};
  for (int n0 = g * 16; n0 < g * 16 + 16; ++n0) {
    ushort4 v = *reinterpret_cast<const ushort4*>(up + n0 * 128 + d4);
    float c = cL[n0];
    a.x += bf2f(v.x) * c; a.y += bf2f(v.y) * c; a.z += bf2f(v.z) * c; a.w += bf2f(v.w) * c;
  }
  *reinterpret_cast<float4*>(&part[g][d4]) = a;
  __syncthreads();
  if (t < 128) {
    float r = part[0][t] + part[1][t] + part[2][t] + part[3][t];
    out[(size_t)bid * 128 + t] = r;
  }
}

extern "C" void kernel_launch(void* const* d_in, const int* in_sizes, int n_in,
                              void* d_out, int out_size, void* d_ws, size_t ws_size,
                              hipStream_t stream) {
  const float* x = (const float*)d_in[0];
  const float* W = (const float*)d_in[1];
  const float* bias = (const float*)d_in[2];
  float* out = (float*)d_out;

  ushort* u = (ushort*)d_ws;                                   // 268435456 B
  float* logits = (float*)((char*)d_ws + 268435456u);          // 4194304 B
  char* ccxbf = (char*)d_ws + 272629760u;                      // 4194304 B shared
  ushort* xbf = (ushort*)ccxbf;     // live Px..K1
  float* cc = (float*)ccxbf;        // live K3..K4 (overwrites xbf after K1 done)

  hipLaunchKernelGGL(px_cvt,     dim3(1024),      dim3(512), 0, stream, x, xbf);
  hipLaunchKernelGGL(k1_gemm,    dim3(NN1 * NN0), dim3(512), 0, stream, xbf, W, u);
  hipLaunchKernelGGL(k2_logits,  dim3(BB * NN1),  dim3(256), 0, stream, u, logits);
  hipLaunchKernelGGL(k3_softmax, dim3(BB),        dim3(64),  0, stream, logits, bias, cc);
  hipLaunchKernelGGL(k4_out,     dim3(BB * NN1),  dim3(128), 0, stream, u, cc, out);
}